// Round 1
// baseline (349.830 us; speedup 1.0000x reference)
//
#include <hip/hip_runtime.h>
#include <stdint.h>

// LinearAttention (literal listing, softmax over n):
//   ctx_h = softmax_n(K_h) @ V_h^T;  out = wout·(ctx^T ⊛ q) + b
//   collapsed: out[b] = Weff[b]@x[b]+b,  Weff = wout·blockdiag(ctx^T)·W_q
// ROUND 11: k1d replaces k1p — barrier-free. Theory: k1p was latency-bound
// (all pipes <12%, occ 31%); XT staging forced 37.9KB LDS (4 blk/CU) and a
// per-tile __syncthreads lockstep. k1d gathers B-frags directly from global
// (same element count as the old ds_read_u16 gather; 4 waves share via L1),
// LDS drops to 20.5KB (EKV only) -> 7 blk/CU, zero barriers, waves fully
// independent. bf16 values bit-identical to staged path.
// k2s pre-sums shadows. k3b unchanged (round-9, passing).

using f32x4 = __attribute__((ext_vector_type(4))) float;
using s16x8 = __attribute__((ext_vector_type(8))) short;

#define NSP 110592  // 48*48*48
#define NSHADOW 16
#define MFMA(a, b, c) __builtin_amdgcn_mfma_f32_16x16x32_bf16((a), (b), (c), 0, 0, 0)

static __device__ __forceinline__ unsigned short f2bf(float f) {
    return (unsigned short)((__float_as_uint(f) + 0x8000u) >> 16);  // round-half-up
}

// ---------------------------------------------------------------------------
// k1d: 1728 blocks (864/batch), 4 contiguous 32-n tiles each, NO barriers.
// Per wave(=head): B-frags loaded straight from global (f32->bf16 in regs),
// GEMM1 via MFMA, exp fp32, Z in regs, wave-private EKV round-trip (in-order
// DS pipe), GEMM2. Flush to shadow S/Z atomics.
// ---------------------------------------------------------------------------
__global__ __launch_bounds__(256, 6) void k1d(
    const float* __restrict__ x, const float* __restrict__ wqkv,
    float* __restrict__ Ssh, float* __restrict__ Zsh)
{
    __shared__ unsigned short EKV[4][2][32][40];  // wave-private [K/V][row][col]
    const int tid = threadIdx.x;
    const int wv = tid >> 6;
    const int l = tid & 63;
    const int l15 = l & 15, l4 = l >> 4;
    const int blk = blockIdx.x;
    const int b = blk / 864;            // 864 blocks/batch
    const int tbase = (blk % 864) * 4;  // 4 contiguous tiles
    const int shadow = blk & (NSHADOW - 1);
    const int h = wv;

    // A-frags: rows of W_k (128+h*32+m) / W_v (256+h*32+m); A[m=l15][k=l4*8+j]
    s16x8 afr[2][2][2];  // [kv][mtile][kstep]
    for (int kv = 0; kv < 2; ++kv)
        for (int mt = 0; mt < 2; ++mt)
            for (int s = 0; s < 2; ++s) {
                int row = 128 + kv * 128 + h * 32 + mt * 16 + l15;
                const float* wp = wqkv + row * 64 + s * 32 + l4 * 8;
                s16x8 a;
#pragma unroll
                for (int j = 0; j < 8; ++j) a[j] = (short)f2bf(wp[j]);
                afr[kv][mt][s] = a;
            }

    f32x4 sacc[2][2] = {};
    float zrow[8] = {};

    unsigned short (*EK)[40] = EKV[wv][0];
    unsigned short (*EV)[40] = EKV[wv][1];
    // per-lane base: row = l4*8 (+s*32+j), col = l15 (+n0, +16 for nt=1)
    const float* xq = x + (size_t)b * 64 * NSP + (size_t)(l4 * 8) * NSP + l15;

    for (int it = 0; it < 4; ++it) {
        const int n0 = (tbase + it) * 32;
        f32x4 ck[2][2] = {}, cv[2][2] = {};
#pragma unroll
        for (int s = 0; s < 2; ++s) {
            // 16 independent dword loads (batched), then convert
            float t0[8], t1[8];
#pragma unroll
            for (int j = 0; j < 8; ++j) {
                const float* p = xq + (size_t)(s * 32 + j) * NSP + n0;
                t0[j] = p[0];    // nt=0 column
                t1[j] = p[16];   // nt=1 column
            }
            s16x8 b0, b1;  // B[k=s*32+l4*8+j][n=nt*16+l15]
#pragma unroll
            for (int j = 0; j < 8; ++j) {
                b0[j] = (short)f2bf(t0[j]);
                b1[j] = (short)f2bf(t1[j]);
            }
#pragma unroll
            for (int mt = 0; mt < 2; ++mt) {
                ck[mt][0] = MFMA(afr[0][mt][s], b0, ck[mt][0]);
                cv[mt][0] = MFMA(afr[1][mt][s], b0, cv[mt][0]);
                ck[mt][1] = MFMA(afr[0][mt][s], b1, ck[mt][1]);
                cv[mt][1] = MFMA(afr[1][mt][s], b1, cv[mt][1]);
            }
        }
        // exp -> Z(regs) + EK; V -> EV   (C: row=mt*16+l4*4+r, col=nt*16+l15)
#pragma unroll
        for (int mt = 0; mt < 2; ++mt)
#pragma unroll
            for (int nt = 0; nt < 2; ++nt) {
                int col = nt * 16 + l15;
#pragma unroll
                for (int r = 0; r < 4; ++r) {
                    int row = mt * 16 + l4 * 4 + r;
                    float ek = __expf(ck[mt][nt][r]);
                    zrow[mt * 4 + r] += ek;
                    EK[row][col] = f2bf(ek);
                    EV[row][col] = f2bf(cv[mt][nt][r]);
                }
            }
        // GEMM2: S_h += expK(32x32) @ V^T (wave-private, in-order DS pipe)
#pragma unroll
        for (int td = 0; td < 2; ++td) {
            s16x8 a2 = *(const s16x8*)&EK[td * 16 + l15][l4 * 8];
#pragma unroll
            for (int te = 0; te < 2; ++te) {
                s16x8 b2 = *(const s16x8*)&EV[te * 16 + l15][l4 * 8];
                sacc[td][te] = MFMA(a2, b2, sacc[td][te]);
            }
        }
    }

    // Z: butterfly over the 16 replicating l15 lanes, one atomic per row
#pragma unroll
    for (int i = 0; i < 8; ++i) {
        float z = zrow[i];
        z += __shfl_xor(z, 1);
        z += __shfl_xor(z, 2);
        z += __shfl_xor(z, 4);
        z += __shfl_xor(z, 8);
        zrow[i] = z;
    }
    float* Zb = Zsh + (size_t)(shadow * 2 + b) * 128;
    if (l15 == 0)
#pragma unroll
        for (int mt = 0; mt < 2; ++mt)
#pragma unroll
            for (int r = 0; r < 4; ++r)
                atomicAdd(&Zb[h * 32 + mt * 16 + l4 * 4 + r], zrow[mt * 4 + r]);

    float* Sb = Ssh + (size_t)(shadow * 2 + b) * 4096 + h * 1024;
#pragma unroll
    for (int td = 0; td < 2; ++td)
#pragma unroll
        for (int te = 0; te < 2; ++te)
#pragma unroll
            for (int r = 0; r < 4; ++r)
                atomicAdd(&Sb[(td * 16 + l4 * 4 + r) * 32 + te * 16 + l15],
                          sacc[td][te][r]);
}

// ---------------------------------------------------------------------------
// k2s: sum 16 shadows -> ctx = S/Z; P[c][hd] = sum_e wout[c][h*32+e]*ctx[h][d][e];
//      Weff[c][c2] = sum_hd P[c][hd]*wqkv[hd][c2] -> bf16
// ---------------------------------------------------------------------------
__global__ __launch_bounds__(1024) void k2s(
    const float* __restrict__ Ssh, const float* __restrict__ Zsh,
    const float* __restrict__ wout, const float* __restrict__ wqkv,
    unsigned short* __restrict__ WE)
{
    __shared__ float ctx[4][32][32];
    __shared__ float P[64][128];
    __shared__ float Zl[128];
    const int b = blockIdx.x;
    const int t = threadIdx.x;
    if (t < 128) {
        float z = 0.f;
#pragma unroll
        for (int s = 0; s < NSHADOW; ++s) z += Zsh[(size_t)(s * 2 + b) * 128 + t];
        Zl[t] = z;
    }
    __syncthreads();
    for (int i = t; i < 4096; i += 1024) {
        float sv = 0.f;
#pragma unroll
        for (int s = 0; s < NSHADOW; ++s) sv += Ssh[(size_t)(s * 2 + b) * 4096 + i];
        int h = i >> 10, d = (i >> 5) & 31;
        ctx[h][d][i & 31] = sv / Zl[h * 32 + d];
    }
    __syncthreads();
    for (int i = t; i < 8192; i += 1024) {
        int c = i >> 7, hd = i & 127, h = hd >> 5, d = hd & 31;
        const float* wo = wout + c * 128 + h * 32;
        float acc = 0.f;
#pragma unroll 8
        for (int e = 0; e < 32; ++e) acc += wo[e] * ctx[h][d][e];
        P[c][hd] = acc;
    }
    __syncthreads();
    for (int i = t; i < 4096; i += 1024) {
        int c = i >> 6, c2 = i & 63;
        float acc = 0.f;
#pragma unroll 8
        for (int hd = 0; hd < 128; ++hd) acc += P[c][hd] * wqkv[hd * 64 + c2];
        WE[b * 4096 + c * 64 + c2] = f2bf(acc);
    }
}

// ---------------------------------------------------------------------------
// k3b (unchanged, round 9): out[b] = Weff[b]@x[b] + bias. 1728 blocks x
// 128-col strips; staged XT, MFMA, OT transpose, coalesced float4 stores.
// ---------------------------------------------------------------------------
__global__ __launch_bounds__(256) void k3b(
    const float* __restrict__ x, const unsigned short* __restrict__ WE,
    const float* __restrict__ bout, float* __restrict__ out)
{
    __shared__ unsigned short XT[64][132];
    __shared__ float OT[64][136];
    const int tid = threadIdx.x;
    const int wv = tid >> 6;
    const int l = tid & 63;
    const int l15 = l & 15, l4 = l >> 4;
    const int b = blockIdx.x / 864;
    const int n0 = (blockIdx.x % 864) * 128;

    s16x8 afr[4][2];
#pragma unroll
    for (int mt = 0; mt < 4; ++mt)
#pragma unroll
        for (int s = 0; s < 2; ++s)
            afr[mt][s] = *(const s16x8*)(WE + b * 4096 + (mt * 16 + l15) * 64 + s * 32 + l4 * 8);

    float bias[4][4];
#pragma unroll
    for (int mt = 0; mt < 4; ++mt)
#pragma unroll
        for (int r = 0; r < 4; ++r) bias[mt][r] = bout[mt * 16 + l4 * 4 + r];

    const float* xb = x + (size_t)b * 64 * NSP;
    float* ob = out + (size_t)b * 64 * NSP;

#pragma unroll
    for (int p = 0; p < 8; ++p) {
        int idx = tid + 256 * p;
        int c = idx >> 5, ng = idx & 31;
        float4 v = *(const float4*)(xb + (size_t)c * NSP + n0 + 4 * ng);
        ushort4 u;
        u.x = f2bf(v.x); u.y = f2bf(v.y); u.z = f2bf(v.z); u.w = f2bf(v.w);
        *(ushort4*)&XT[c][4 * ng] = u;
    }
    __syncthreads();

    const int nq = wv * 32;
    f32x4 acc[4][2] = {};
#pragma unroll
    for (int s = 0; s < 2; ++s)
#pragma unroll
        for (int nt = 0; nt < 2; ++nt) {
            s16x8 bfr;
#pragma unroll
            for (int j = 0; j < 8; ++j)
                bfr[j] = (short)XT[s * 32 + l4 * 8 + j][nq + nt * 16 + l15];
#pragma unroll
            for (int mt = 0; mt < 4; ++mt) acc[mt][nt] = MFMA(afr[mt][s], bfr, acc[mt][nt]);
        }
#pragma unroll
    for (int mt = 0; mt < 4; ++mt)
#pragma unroll
        for (int nt = 0; nt < 2; ++nt)
#pragma unroll
            for (int r = 0; r < 4; ++r)
                OT[mt * 16 + l4 * 4 + r][nq + nt * 16 + l15] = acc[mt][nt][r] + bias[mt][r];
    __syncthreads();

#pragma unroll
    for (int p = 0; p < 8; ++p) {
        int idx = tid + 256 * p;
        int c = idx >> 5, ng = idx & 31;
        float4 v = *(const float4*)&OT[c][4 * ng];
        *(float4*)(ob + (size_t)c * NSP + n0 + 4 * ng) = v;
    }
}

extern "C" void kernel_launch(void* const* d_in, const int* in_sizes, int n_in,
                              void* d_out, int out_size, void* d_ws, size_t ws_size,
                              hipStream_t stream) {
    // Inputs by size (order-proof): x=14155776, w_qkv=24576, w_out=8192, b_out=64.
    const float *x = nullptr, *wqkv = nullptr, *wout = nullptr, *bout = nullptr;
    for (int i = 0; i < n_in; ++i) {
        if (in_sizes[i] == 2 * 64 * NSP) x = (const float*)d_in[i];
        else if (in_sizes[i] == 384 * 64) wqkv = (const float*)d_in[i];
        else if (in_sizes[i] == 64 * 128) wout = (const float*)d_in[i];
        else if (in_sizes[i] == 64) bout = (const float*)d_in[i];
    }
    if (!x) x = (const float*)d_in[0];
    if (!wqkv) wqkv = (const float*)d_in[1];
    if (!wout) wout = (const float*)d_in[2];
    if (!bout) bout = (const float*)d_in[3];
    float* out = (float*)d_out;

    // ws: Ssh fp32[16][2][4096] @0 (512KB), Zsh fp32[16][2][128] @524288 (16KB),
    //     WE bf16[2][4096] @540672 (16KB)
    float* Ssh = (float*)d_ws;
    float* Zsh = (float*)((char*)d_ws + 524288);
    unsigned short* WE = (unsigned short*)((char*)d_ws + 540672);

    hipMemsetAsync(d_ws, 0, 540672, stream);  // zero shadows (ws poisoned 0xAA)
    hipLaunchKernelGGL(k1d, dim3(1728), dim3(256), 0, stream, x, wqkv, Ssh, Zsh);
    hipLaunchKernelGGL(k2s, dim3(2), dim3(1024), 0, stream, Ssh, Zsh, wout, wqkv, WE);
    hipLaunchKernelGGL(k3b, dim3(1728), dim3(256), 0, stream, x, WE, bout, out);
}

// Round 2
// 238.439 us; speedup vs baseline: 1.4672x; 1.4672x over previous
//
#include <hip/hip_runtime.h>
#include <stdint.h>

// LinearAttention (literal listing, softmax over n):
//   ctx_h = softmax_n(K_h) @ V_h^T;  out = wout·(ctx^T ⊛ q) + b
//   collapsed: out[b] = Weff[b]@x[b]+b,  Weff = wout·blockdiag(ctx^T)·W_q
// ROUND 12: revert round-11 (k1d spilled to scratch: WRITE 277MB, and the
// 4 waves re-fetched x 4x: FETCH 218MB -> 203us). k1t = k1p structure with:
//  (a) 864 blocks x 8 tiles: atomics halved to 3.57M (k1p WRITE==atomic
//      bytes -> atomics write through to HBM; suspected serializer), and
//      all blocks resident in one round (no 1.69-round tail).
//  (b) TRANSPOSED staging XTt[n][c]: B-frag = 8 contiguous bf16 -> 2x
//      ds_read_b64 per (s,nt) (8/tile) replacing 32 ds_read_u16 + pack VALU.
//  (c) LDS 37.9KB -> 29.2KB -> 5 blocks/CU (launch_bounds(256,5)).
// k2s pre-sums shadows. k3b unchanged (round-9, passing).

using f32x4 = __attribute__((ext_vector_type(4))) float;
using s16x8 = __attribute__((ext_vector_type(8))) short;
using s16x4 = __attribute__((ext_vector_type(4))) short;

#define NSP 110592  // 48*48*48
#define NSHADOW 16
#define MFMA(a, b, c) __builtin_amdgcn_mfma_f32_16x16x32_bf16((a), (b), (c), 0, 0, 0)

static __device__ __forceinline__ unsigned short f2bf(float f) {
    return (unsigned short)((__float_as_uint(f) + 0x8000u) >> 16);  // round-half-up
}

// ---------------------------------------------------------------------------
// k1t: 864 blocks (432/batch), each: 8 contiguous 32-n tiles, software-
// pipelined (dbuf XTt, 1 barrier/iter, cross-tile prefetch). Staged tile is
// TRANSPOSED: XTt[n=32][c=64(+4 pad)] so B-frags are contiguous b64 reads.
// Per wave(=head): GEMM1 via MFMA, exp fp32, Z in regs, wave-private EKV
// round-trip (in-order DS pipe), GEMM2. One atomic flush per block.
// ---------------------------------------------------------------------------
__global__ __launch_bounds__(256, 5) void k1t(
    const float* __restrict__ x, const float* __restrict__ wqkv,
    float* __restrict__ Ssh, float* __restrict__ Zsh)
{
    __shared__ unsigned short XTt[2][32][68];     // dbuf staged tile, [n][c]
    __shared__ unsigned short EKV[4][2][32][40];  // wave-private [K/V][row][col]
    const int tid = threadIdx.x;
    const int wv = tid >> 6;
    const int l = tid & 63;
    const int l15 = l & 15, l4 = l >> 4;
    const int blk = blockIdx.x;
    const int b = blk / 432;            // 432 blocks/batch
    const int tbase = (blk % 432) * 8;  // 8 contiguous tiles
    const int shadow = blk & (NSHADOW - 1);
    const int h = wv;

    // A-frags: rows of W_k (128+h*32+m) / W_v (256+h*32+m); A[m=l15][k=l4*8+j]
    s16x8 afr[2][2][2];  // [kv][mtile][kstep]
    for (int kv = 0; kv < 2; ++kv)
        for (int mt = 0; mt < 2; ++mt)
            for (int s = 0; s < 2; ++s) {
                int row = 128 + kv * 128 + h * 32 + mt * 16 + l15;
                const float* wp = wqkv + row * 64 + s * 32 + l4 * 8;
                s16x8 a;
#pragma unroll
                for (int j = 0; j < 8; ++j) a[j] = (short)f2bf(wp[j]);
                afr[kv][mt][s] = a;
            }

    f32x4 sacc[2][2] = {};
    float zrow[8] = {};

    unsigned short (*EK)[40] = EKV[wv][0];
    unsigned short (*EV)[40] = EKV[wv][1];
    const float* xb = x + (size_t)b * 64 * NSP;

    // staging: thread t loads 2 float4 (rows c0/c1, 16B chunk ng within tile)
    const int c0 = tid >> 3;          // p=0: c = 0..31
    const int c1 = c0 + 32;           // p=1: c = 32..63
    const int ng = tid & 7;           // 16B chunk -> n = 4*ng..4*ng+3

    float4 g0, g1;
    {   // preload tile 0
        const int n0 = tbase * 32;
        g0 = *(const float4*)(xb + (size_t)c0 * NSP + n0 + 4 * ng);
        g1 = *(const float4*)(xb + (size_t)c1 * NSP + n0 + 4 * ng);
    }

    for (int it = 0; it < 8; ++it) {
        unsigned short (*XB)[68] = XTt[it & 1];
        // write staged regs -> XTt[buf] (transposed: row n, col c)
        XB[4 * ng + 0][c0] = f2bf(g0.x);
        XB[4 * ng + 1][c0] = f2bf(g0.y);
        XB[4 * ng + 2][c0] = f2bf(g0.z);
        XB[4 * ng + 3][c0] = f2bf(g0.w);
        XB[4 * ng + 0][c1] = f2bf(g1.x);
        XB[4 * ng + 1][c1] = f2bf(g1.y);
        XB[4 * ng + 2][c1] = f2bf(g1.z);
        XB[4 * ng + 3][c1] = f2bf(g1.w);
        // issue next tile's loads; they fly across the barrier + compute
        if (it < 7) {
            const int n0 = (tbase + it + 1) * 32;
            g0 = *(const float4*)(xb + (size_t)c0 * NSP + n0 + 4 * ng);
            g1 = *(const float4*)(xb + (size_t)c1 * NSP + n0 + 4 * ng);
        }
        __syncthreads();

        // GEMM1: [K_h;V_h] = W @ xtile (M=64,K=64,N=32); B-frag contiguous
        f32x4 ck[2][2] = {}, cv[2][2] = {};
#pragma unroll
        for (int s = 0; s < 2; ++s)
#pragma unroll
            for (int nt = 0; nt < 2; ++nt) {
                const unsigned short* rp = &XB[nt * 16 + l15][s * 32 + l4 * 8];
                s16x4 lo = *(const s16x4*)rp;
                s16x4 hi = *(const s16x4*)(rp + 4);
                s16x8 bfr = __builtin_shufflevector(lo, hi, 0, 1, 2, 3, 4, 5, 6, 7);
#pragma unroll
                for (int mt = 0; mt < 2; ++mt) {
                    ck[mt][nt] = MFMA(afr[0][mt][s], bfr, ck[mt][nt]);
                    cv[mt][nt] = MFMA(afr[1][mt][s], bfr, cv[mt][nt]);
                }
            }
        // exp -> Z(regs) + EK; V -> EV   (C: row=mt*16+l4*4+r, col=nt*16+l15)
#pragma unroll
        for (int mt = 0; mt < 2; ++mt)
#pragma unroll
            for (int nt = 0; nt < 2; ++nt) {
                int col = nt * 16 + l15;
#pragma unroll
                for (int r = 0; r < 4; ++r) {
                    int row = mt * 16 + l4 * 4 + r;
                    float ek = __expf(ck[mt][nt][r]);
                    zrow[mt * 4 + r] += ek;
                    EK[row][col] = f2bf(ek);
                    EV[row][col] = f2bf(cv[mt][nt][r]);
                }
            }
        // GEMM2: S_h += expK(32x32) @ V^T (wave-private, in-order DS pipe)
#pragma unroll
        for (int td = 0; td < 2; ++td) {
            s16x8 a2 = *(const s16x8*)&EK[td * 16 + l15][l4 * 8];
#pragma unroll
            for (int te = 0; te < 2; ++te) {
                s16x8 b2 = *(const s16x8*)&EV[te * 16 + l15][l4 * 8];
                sacc[td][te] = MFMA(a2, b2, sacc[td][te]);
            }
        }
        // no second barrier: next iter writes the other XTt buffer
    }

    // Z: butterfly over the 16 replicating l15 lanes, one atomic per row
#pragma unroll
    for (int i = 0; i < 8; ++i) {
        float z = zrow[i];
        z += __shfl_xor(z, 1);
        z += __shfl_xor(z, 2);
        z += __shfl_xor(z, 4);
        z += __shfl_xor(z, 8);
        zrow[i] = z;
    }
    float* Zb = Zsh + (size_t)(shadow * 2 + b) * 128;
    if (l15 == 0)
#pragma unroll
        for (int mt = 0; mt < 2; ++mt)
#pragma unroll
            for (int r = 0; r < 4; ++r)
                atomicAdd(&Zb[h * 32 + mt * 16 + l4 * 4 + r], zrow[mt * 4 + r]);

    float* Sb = Ssh + (size_t)(shadow * 2 + b) * 4096 + h * 1024;
#pragma unroll
    for (int td = 0; td < 2; ++td)
#pragma unroll
        for (int te = 0; te < 2; ++te)
#pragma unroll
            for (int r = 0; r < 4; ++r)
                atomicAdd(&Sb[(td * 16 + l4 * 4 + r) * 32 + te * 16 + l15],
                          sacc[td][te][r]);
}

// ---------------------------------------------------------------------------
// k2s: sum 16 shadows -> ctx = S/Z; P[c][hd] = sum_e wout[c][h*32+e]*ctx[h][d][e];
//      Weff[c][c2] = sum_hd P[c][hd]*wqkv[hd][c2] -> bf16
// ---------------------------------------------------------------------------
__global__ __launch_bounds__(1024) void k2s(
    const float* __restrict__ Ssh, const float* __restrict__ Zsh,
    const float* __restrict__ wout, const float* __restrict__ wqkv,
    unsigned short* __restrict__ WE)
{
    __shared__ float ctx[4][32][32];
    __shared__ float P[64][128];
    __shared__ float Zl[128];
    const int b = blockIdx.x;
    const int t = threadIdx.x;
    if (t < 128) {
        float z = 0.f;
#pragma unroll
        for (int s = 0; s < NSHADOW; ++s) z += Zsh[(size_t)(s * 2 + b) * 128 + t];
        Zl[t] = z;
    }
    __syncthreads();
    for (int i = t; i < 4096; i += 1024) {
        float sv = 0.f;
#pragma unroll
        for (int s = 0; s < NSHADOW; ++s) sv += Ssh[(size_t)(s * 2 + b) * 4096 + i];
        int h = i >> 10, d = (i >> 5) & 31;
        ctx[h][d][i & 31] = sv / Zl[h * 32 + d];
    }
    __syncthreads();
    for (int i = t; i < 8192; i += 1024) {
        int c = i >> 7, hd = i & 127, h = hd >> 5, d = hd & 31;
        const float* wo = wout + c * 128 + h * 32;
        float acc = 0.f;
#pragma unroll 8
        for (int e = 0; e < 32; ++e) acc += wo[e] * ctx[h][d][e];
        P[c][hd] = acc;
    }
    __syncthreads();
    for (int i = t; i < 4096; i += 1024) {
        int c = i >> 6, c2 = i & 63;
        float acc = 0.f;
#pragma unroll 8
        for (int hd = 0; hd < 128; ++hd) acc += P[c][hd] * wqkv[hd * 64 + c2];
        WE[b * 4096 + c * 64 + c2] = f2bf(acc);
    }
}

// ---------------------------------------------------------------------------
// k3b (unchanged, round 9): out[b] = Weff[b]@x[b] + bias. 1728 blocks x
// 128-col strips; staged XT, MFMA, OT transpose, coalesced float4 stores.
// ---------------------------------------------------------------------------
__global__ __launch_bounds__(256) void k3b(
    const float* __restrict__ x, const unsigned short* __restrict__ WE,
    const float* __restrict__ bout, float* __restrict__ out)
{
    __shared__ unsigned short XT[64][132];
    __shared__ float OT[64][136];
    const int tid = threadIdx.x;
    const int wv = tid >> 6;
    const int l = tid & 63;
    const int l15 = l & 15, l4 = l >> 4;
    const int b = blockIdx.x / 864;
    const int n0 = (blockIdx.x % 864) * 128;

    s16x8 afr[4][2];
#pragma unroll
    for (int mt = 0; mt < 4; ++mt)
#pragma unroll
        for (int s = 0; s < 2; ++s)
            afr[mt][s] = *(const s16x8*)(WE + b * 4096 + (mt * 16 + l15) * 64 + s * 32 + l4 * 8);

    float bias[4][4];
#pragma unroll
    for (int mt = 0; mt < 4; ++mt)
#pragma unroll
        for (int r = 0; r < 4; ++r) bias[mt][r] = bout[mt * 16 + l4 * 4 + r];

    const float* xb = x + (size_t)b * 64 * NSP;
    float* ob = out + (size_t)b * 64 * NSP;

#pragma unroll
    for (int p = 0; p < 8; ++p) {
        int idx = tid + 256 * p;
        int c = idx >> 5, ng = idx & 31;
        float4 v = *(const float4*)(xb + (size_t)c * NSP + n0 + 4 * ng);
        ushort4 u;
        u.x = f2bf(v.x); u.y = f2bf(v.y); u.z = f2bf(v.z); u.w = f2bf(v.w);
        *(ushort4*)&XT[c][4 * ng] = u;
    }
    __syncthreads();

    const int nq = wv * 32;
    f32x4 acc[4][2] = {};
#pragma unroll
    for (int s = 0; s < 2; ++s)
#pragma unroll
        for (int nt = 0; nt < 2; ++nt) {
            s16x8 bfr;
#pragma unroll
            for (int j = 0; j < 8; ++j)
                bfr[j] = (short)XT[s * 32 + l4 * 8 + j][nq + nt * 16 + l15];
#pragma unroll
            for (int mt = 0; mt < 4; ++mt) acc[mt][nt] = MFMA(afr[mt][s], bfr, acc[mt][nt]);
        }
#pragma unroll
    for (int mt = 0; mt < 4; ++mt)
#pragma unroll
        for (int nt = 0; nt < 2; ++nt)
#pragma unroll
            for (int r = 0; r < 4; ++r)
                OT[mt * 16 + l4 * 4 + r][nq + nt * 16 + l15] = acc[mt][nt][r] + bias[mt][r];
    __syncthreads();

#pragma unroll
    for (int p = 0; p < 8; ++p) {
        int idx = tid + 256 * p;
        int c = idx >> 5, ng = idx & 31;
        float4 v = *(const float4*)&OT[c][4 * ng];
        *(float4*)(ob + (size_t)c * NSP + n0 + 4 * ng) = v;
    }
}

extern "C" void kernel_launch(void* const* d_in, const int* in_sizes, int n_in,
                              void* d_out, int out_size, void* d_ws, size_t ws_size,
                              hipStream_t stream) {
    // Inputs by size (order-proof): x=14155776, w_qkv=24576, w_out=8192, b_out=64.
    const float *x = nullptr, *wqkv = nullptr, *wout = nullptr, *bout = nullptr;
    for (int i = 0; i < n_in; ++i) {
        if (in_sizes[i] == 2 * 64 * NSP) x = (const float*)d_in[i];
        else if (in_sizes[i] == 384 * 64) wqkv = (const float*)d_in[i];
        else if (in_sizes[i] == 64 * 128) wout = (const float*)d_in[i];
        else if (in_sizes[i] == 64) bout = (const float*)d_in[i];
    }
    if (!x) x = (const float*)d_in[0];
    if (!wqkv) wqkv = (const float*)d_in[1];
    if (!wout) wout = (const float*)d_in[2];
    if (!bout) bout = (const float*)d_in[3];
    float* out = (float*)d_out;

    // ws: Ssh fp32[16][2][4096] @0 (512KB), Zsh fp32[16][2][128] @524288 (16KB),
    //     WE bf16[2][4096] @540672 (16KB)
    float* Ssh = (float*)d_ws;
    float* Zsh = (float*)((char*)d_ws + 524288);
    unsigned short* WE = (unsigned short*)((char*)d_ws + 540672);

    hipMemsetAsync(d_ws, 0, 540672, stream);  // zero shadows (ws poisoned 0xAA)
    hipLaunchKernelGGL(k1t, dim3(864), dim3(256), 0, stream, x, wqkv, Ssh, Zsh);
    hipLaunchKernelGGL(k2s, dim3(2), dim3(1024), 0, stream, Ssh, Zsh, wout, wqkv, WE);
    hipLaunchKernelGGL(k3b, dim3(1728), dim3(256), 0, stream, x, WE, bout, out);
}

// Round 3
// 182.170 us; speedup vs baseline: 1.9203x; 1.3089x over previous
//
#include <hip/hip_runtime.h>
#include <stdint.h>

// LinearAttention (literal listing, softmax over n):
//   ctx_h = softmax_n(K_h) @ V_h^T;  out = wout·(ctx^T ⊛ q) + b
//   collapsed: out[b] = Weff[b]@x[b]+b,  Weff = wout·blockdiag(ctx^T)·W_q
// ROUND 13:
//  * Round-12 post-mortem: transposed staging spilled (VGPR 48, +140MB scratch
//    traffic) and scalar u16 LDS writes raised bank conflicts. Reverted.
//  * Pipeline accounting: total-k1 is ~142us in ALL rounds -> k3b is ~110-125us
//    (bigger than k1!). k3c: kill the OT LDS round-trip, store MFMA results
//    directly (4x64B segments/instr), LDS 51.7->16.9KB (3->8 blk/CU), 1 barrier.
//  * k1u = round-0 k1p body verbatim, but 864 blocks x 8 tiles (all-resident,
//    no tail) and NON-ATOMIC flush when ws allows: per-block S partial stores
//    (removes ~3.5M atomic issues ~ 13us/CU of VMEM issue), reduced by new
//    k2pre (432 partials -> 16 intermediates), then unchanged k2s.
//    Fallback to shadow atomics if ws_size < 15.2MB.

using f32x4 = __attribute__((ext_vector_type(4))) float;
using s16x8 = __attribute__((ext_vector_type(8))) short;

#define NSP 110592  // 48*48*48
#define NSHADOW 16
#define MFMA(a, b, c) __builtin_amdgcn_mfma_f32_16x16x32_bf16((a), (b), (c), 0, 0, 0)

static __device__ __forceinline__ unsigned short f2bf(float f) {
    return (unsigned short)((__float_as_uint(f) + 0x8000u) >> 16);  // round-half-up
}

// ---------------------------------------------------------------------------
// k1u: 864 blocks (432/batch), each: 8 contiguous 32-n tiles, software-
// pipelined (dbuf XT, 1 barrier/iter, cross-tile prefetch). Round-0 k1p body.
// mode 0: flush per-block partials (plain stores) to Sp[blk]/Zp[blk].
// mode 1: atomic flush into 16-shadow S/Z (round-0 scheme).
// ---------------------------------------------------------------------------
__global__ __launch_bounds__(256, 4) void k1u(
    const float* __restrict__ x, const float* __restrict__ wqkv,
    float* __restrict__ Sdst, float* __restrict__ Zdst, int mode)
{
    __shared__ unsigned short XT[2][64][68];      // dbuf staged x tile (bf16)
    __shared__ unsigned short EKV[4][2][32][40];  // wave-private [K/V][row][col]
    const int tid = threadIdx.x;
    const int wv = tid >> 6;
    const int l = tid & 63;
    const int l15 = l & 15, l4 = l >> 4;
    const int blk = blockIdx.x;
    const int b = blk / 432;            // 432 blocks/batch
    const int tbase = (blk % 432) * 8;  // 8 contiguous tiles
    const int h = wv;

    // A-frags: rows of W_k (128+h*32+m) / W_v (256+h*32+m); A[m=l15][k=l4*8+j]
    s16x8 afr[2][2][2];  // [kv][mtile][kstep]
    for (int kv = 0; kv < 2; ++kv)
        for (int mt = 0; mt < 2; ++mt)
            for (int s = 0; s < 2; ++s) {
                int row = 128 + kv * 128 + h * 32 + mt * 16 + l15;
                const float* wp = wqkv + row * 64 + s * 32 + l4 * 8;
                s16x8 a;
#pragma unroll
                for (int j = 0; j < 8; ++j) a[j] = (short)f2bf(wp[j]);
                afr[kv][mt][s] = a;
            }

    f32x4 sacc[2][2] = {};
    float zrow[8] = {};

    unsigned short (*EK)[40] = EKV[wv][0];
    unsigned short (*EV)[40] = EKV[wv][1];
    const float* xb = x + (size_t)b * 64 * NSP;

    // staging addresses for this thread (2 float4 per tile)
    const int c0 = tid >> 3;                        // p=0 row
    const int ng0 = (tid & 7) ^ (c0 & 7);
    const int c1 = (tid + 256) >> 3;                // p=1 row
    const int ng1 = ((tid + 256) & 7) ^ (c1 & 7);

    float4 g0, g1;
    {   // preload tile 0
        const int n0 = tbase * 32;
        g0 = *(const float4*)(xb + (size_t)c0 * NSP + n0 + 4 * ng0);
        g1 = *(const float4*)(xb + (size_t)c1 * NSP + n0 + 4 * ng1);
    }

    for (int it = 0; it < 8; ++it) {
        unsigned short (*XB)[68] = XT[it & 1];
        // write staged regs -> XT[buf]
        {
            ushort4 u;
            u.x = f2bf(g0.x); u.y = f2bf(g0.y); u.z = f2bf(g0.z); u.w = f2bf(g0.w);
            *(ushort4*)&XB[c0][4 * ng0] = u;
            u.x = f2bf(g1.x); u.y = f2bf(g1.y); u.z = f2bf(g1.z); u.w = f2bf(g1.w);
            *(ushort4*)&XB[c1][4 * ng1] = u;
        }
        // issue next tile's loads; they fly across the barrier + compute
        if (it < 7) {
            const int n0 = (tbase + it + 1) * 32;
            g0 = *(const float4*)(xb + (size_t)c0 * NSP + n0 + 4 * ng0);
            g1 = *(const float4*)(xb + (size_t)c1 * NSP + n0 + 4 * ng1);
        }
        __syncthreads();

        // GEMM1: [K_h;V_h] = W @ xtile (M=64,K=64,N=32)
        f32x4 ck[2][2] = {}, cv[2][2] = {};
#pragma unroll
        for (int s = 0; s < 2; ++s)
#pragma unroll
            for (int nt = 0; nt < 2; ++nt) {
                s16x8 bfr;  // B[k=c][n]: n=l15, c=l4*8+j (+32s)
#pragma unroll
                for (int j = 0; j < 8; ++j)
                    bfr[j] = (short)XB[s * 32 + l4 * 8 + j][nt * 16 + l15];
#pragma unroll
                for (int mt = 0; mt < 2; ++mt) {
                    ck[mt][nt] = MFMA(afr[0][mt][s], bfr, ck[mt][nt]);
                    cv[mt][nt] = MFMA(afr[1][mt][s], bfr, cv[mt][nt]);
                }
            }
        // exp -> Z(regs) + EK; V -> EV   (C: row=mt*16+l4*4+r, col=nt*16+l15)
#pragma unroll
        for (int mt = 0; mt < 2; ++mt)
#pragma unroll
            for (int nt = 0; nt < 2; ++nt) {
                int col = nt * 16 + l15;
#pragma unroll
                for (int r = 0; r < 4; ++r) {
                    int row = mt * 16 + l4 * 4 + r;
                    float ek = __expf(ck[mt][nt][r]);
                    zrow[mt * 4 + r] += ek;
                    EK[row][col] = f2bf(ek);
                    EV[row][col] = f2bf(cv[mt][nt][r]);
                }
            }
        // GEMM2: S_h += expK(32x32) @ V^T (wave-private, in-order DS pipe)
#pragma unroll
        for (int td = 0; td < 2; ++td) {
            s16x8 a2 = *(const s16x8*)&EK[td * 16 + l15][l4 * 8];
#pragma unroll
            for (int te = 0; te < 2; ++te) {
                s16x8 b2 = *(const s16x8*)&EV[te * 16 + l15][l4 * 8];
                sacc[td][te] = MFMA(a2, b2, sacc[td][te]);
            }
        }
        // no second barrier: next iter writes the other XT buffer
    }

    // Z: butterfly over the 16 replicating l15 lanes
#pragma unroll
    for (int i = 0; i < 8; ++i) {
        float z = zrow[i];
        z += __shfl_xor(z, 1);
        z += __shfl_xor(z, 2);
        z += __shfl_xor(z, 4);
        z += __shfl_xor(z, 8);
        zrow[i] = z;
    }

    if (mode == 0) {
        // per-block partial: plain stores, fully written, no zeroing needed
        float* Zb = Zdst + (size_t)blk * 128;
        if (l15 == 0)
#pragma unroll
            for (int mt = 0; mt < 2; ++mt)
#pragma unroll
                for (int r = 0; r < 4; ++r)
                    Zb[h * 32 + mt * 16 + l4 * 4 + r] = zrow[mt * 4 + r];
        float* Sb = Sdst + (size_t)blk * 4096 + h * 1024;
#pragma unroll
        for (int td = 0; td < 2; ++td)
#pragma unroll
            for (int te = 0; te < 2; ++te)
#pragma unroll
                for (int r = 0; r < 4; ++r)
                    Sb[(td * 16 + l4 * 4 + r) * 32 + te * 16 + l15] =
                        sacc[td][te][r];
    } else {
        const int shadow = blk & (NSHADOW - 1);
        float* Zb = Zdst + (size_t)(shadow * 2 + b) * 128;
        if (l15 == 0)
#pragma unroll
            for (int mt = 0; mt < 2; ++mt)
#pragma unroll
                for (int r = 0; r < 4; ++r)
                    atomicAdd(&Zb[h * 32 + mt * 16 + l4 * 4 + r], zrow[mt * 4 + r]);
        float* Sb = Sdst + (size_t)(shadow * 2 + b) * 4096 + h * 1024;
#pragma unroll
        for (int td = 0; td < 2; ++td)
#pragma unroll
            for (int te = 0; te < 2; ++te)
#pragma unroll
                for (int r = 0; r < 4; ++r)
                    atomicAdd(&Sb[(td * 16 + l4 * 4 + r) * 32 + te * 16 + l15],
                              sacc[td][te][r]);
    }
}

// ---------------------------------------------------------------------------
// k2pre: 32 blocks (16 groups x 2 batches) x 256 threads: sum 27 per-block
// partials -> the 16-intermediate layout k2s already consumes.
// ---------------------------------------------------------------------------
__global__ __launch_bounds__(256) void k2pre(
    const float* __restrict__ Sp, const float* __restrict__ Zp,
    float* __restrict__ Ssh, float* __restrict__ Zsh)
{
    const int b = blockIdx.x & 1;
    const int s = blockIdx.x >> 1;
    const int t = threadIdx.x;
    const int base = b * 432 + s * 27;
    for (int i = t; i < 4096; i += 256) {
        float acc = 0.f;
#pragma unroll
        for (int j = 0; j < 27; ++j) acc += Sp[(size_t)(base + j) * 4096 + i];
        Ssh[(size_t)(s * 2 + b) * 4096 + i] = acc;
    }
    if (t < 128) {
        float acc = 0.f;
#pragma unroll
        for (int j = 0; j < 27; ++j) acc += Zp[(size_t)(base + j) * 128 + t];
        Zsh[(size_t)(s * 2 + b) * 128 + t] = acc;
    }
}

// ---------------------------------------------------------------------------
// k2s: sum 16 shadows -> ctx = S/Z; P[c][hd] = sum_e wout[c][h*32+e]*ctx[h][d][e];
//      Weff[c][c2] = sum_hd P[c][hd]*wqkv[hd][c2] -> bf16
// ---------------------------------------------------------------------------
__global__ __launch_bounds__(1024) void k2s(
    const float* __restrict__ Ssh, const float* __restrict__ Zsh,
    const float* __restrict__ wout, const float* __restrict__ wqkv,
    unsigned short* __restrict__ WE)
{
    __shared__ float ctx[4][32][32];
    __shared__ float P[64][128];
    __shared__ float Zl[128];
    const int b = blockIdx.x;
    const int t = threadIdx.x;
    if (t < 128) {
        float z = 0.f;
#pragma unroll
        for (int s = 0; s < NSHADOW; ++s) z += Zsh[(size_t)(s * 2 + b) * 128 + t];
        Zl[t] = z;
    }
    __syncthreads();
    for (int i = t; i < 4096; i += 1024) {
        float sv = 0.f;
#pragma unroll
        for (int s = 0; s < NSHADOW; ++s) sv += Ssh[(size_t)(s * 2 + b) * 4096 + i];
        int h = i >> 10, d = (i >> 5) & 31;
        ctx[h][d][i & 31] = sv / Zl[h * 32 + d];
    }
    __syncthreads();
    for (int i = t; i < 8192; i += 1024) {
        int c = i >> 7, hd = i & 127, h = hd >> 5, d = hd & 31;
        const float* wo = wout + c * 128 + h * 32;
        float acc = 0.f;
#pragma unroll 8
        for (int e = 0; e < 32; ++e) acc += wo[e] * ctx[h][d][e];
        P[c][hd] = acc;
    }
    __syncthreads();
    for (int i = t; i < 4096; i += 1024) {
        int c = i >> 6, c2 = i & 63;
        float acc = 0.f;
#pragma unroll 8
        for (int hd = 0; hd < 128; ++hd) acc += P[c][hd] * wqkv[hd * 64 + c2];
        WE[b * 4096 + c * 64 + c2] = f2bf(acc);
    }
}

// ---------------------------------------------------------------------------
// k3c: out[b] = Weff[b]@x[b] + bias. 1728 blocks x 128-col strips; staged XT
// (16.9KB LDS only -> 8 blk/CU), MFMA, DIRECT global stores (4x64B segments
// per instr, fully utilized) — no OT round-trip, single barrier.
// ---------------------------------------------------------------------------
__global__ __launch_bounds__(256) void k3c(
    const float* __restrict__ x, const unsigned short* __restrict__ WE,
    const float* __restrict__ bout, float* __restrict__ out)
{
    __shared__ unsigned short XT[64][132];
    const int tid = threadIdx.x;
    const int wv = tid >> 6;
    const int l = tid & 63;
    const int l15 = l & 15, l4 = l >> 4;
    const int b = blockIdx.x / 864;
    const int n0 = (blockIdx.x % 864) * 128;

    s16x8 afr[4][2];
#pragma unroll
    for (int mt = 0; mt < 4; ++mt)
#pragma unroll
        for (int s = 0; s < 2; ++s)
            afr[mt][s] = *(const s16x8*)(WE + b * 4096 + (mt * 16 + l15) * 64 + s * 32 + l4 * 8);

    float bias[4][4];
#pragma unroll
    for (int mt = 0; mt < 4; ++mt)
#pragma unroll
        for (int r = 0; r < 4; ++r) bias[mt][r] = bout[mt * 16 + l4 * 4 + r];

    const float* xb = x + (size_t)b * 64 * NSP;
    float* ob = out + (size_t)b * 64 * NSP;

#pragma unroll
    for (int p = 0; p < 8; ++p) {
        int idx = tid + 256 * p;
        int c = idx >> 5, ng = idx & 31;
        float4 v = *(const float4*)(xb + (size_t)c * NSP + n0 + 4 * ng);
        ushort4 u;
        u.x = f2bf(v.x); u.y = f2bf(v.y); u.z = f2bf(v.z); u.w = f2bf(v.w);
        *(ushort4*)&XT[c][4 * ng] = u;
    }
    __syncthreads();

    const int nq = wv * 32;
    f32x4 acc[4][2] = {};
#pragma unroll
    for (int s = 0; s < 2; ++s)
#pragma unroll
        for (int nt = 0; nt < 2; ++nt) {
            s16x8 bfr;
#pragma unroll
            for (int j = 0; j < 8; ++j)
                bfr[j] = (short)XT[s * 32 + l4 * 8 + j][nq + nt * 16 + l15];
#pragma unroll
            for (int mt = 0; mt < 4; ++mt) acc[mt][nt] = MFMA(afr[mt][s], bfr, acc[mt][nt]);
        }

    // direct stores: for fixed (mt,nt,r) the wave writes 4 rows x 16
    // consecutive floats = 4 fully-utilized 64B segments.
#pragma unroll
    for (int mt = 0; mt < 4; ++mt)
#pragma unroll
        for (int nt = 0; nt < 2; ++nt)
#pragma unroll
            for (int r = 0; r < 4; ++r)
                ob[(size_t)(mt * 16 + l4 * 4 + r) * NSP + n0 + nq + nt * 16 + l15] =
                    acc[mt][nt][r] + bias[mt][r];
}

extern "C" void kernel_launch(void* const* d_in, const int* in_sizes, int n_in,
                              void* d_out, int out_size, void* d_ws, size_t ws_size,
                              hipStream_t stream) {
    // Inputs by size (order-proof): x=14155776, w_qkv=24576, w_out=8192, b_out=64.
    const float *x = nullptr, *wqkv = nullptr, *wout = nullptr, *bout = nullptr;
    for (int i = 0; i < n_in; ++i) {
        if (in_sizes[i] == 2 * 64 * NSP) x = (const float*)d_in[i];
        else if (in_sizes[i] == 384 * 64) wqkv = (const float*)d_in[i];
        else if (in_sizes[i] == 64 * 128) wout = (const float*)d_in[i];
        else if (in_sizes[i] == 64) bout = (const float*)d_in[i];
    }
    if (!x) x = (const float*)d_in[0];
    if (!wqkv) wqkv = (const float*)d_in[1];
    if (!wout) wout = (const float*)d_in[2];
    if (!bout) bout = (const float*)d_in[3];
    float* out = (float*)d_out;

    // big path: Sp[864][4096] @0 (14155776B), Zp[864][128] @14155776 (442368B),
    //           Ssh @14598144 (524288B), Zsh @15122432 (16384B), WE @15138816
    // small path (fallback): Ssh @0, Zsh @524288, WE @540672 (round-0 layout)
    const size_t NEED_BIG = 15155200;
    if (ws_size >= NEED_BIG) {
        float* Sp = (float*)d_ws;
        float* Zp = (float*)((char*)d_ws + 14155776);
        float* Ssh = (float*)((char*)d_ws + 14598144);
        float* Zsh = (float*)((char*)d_ws + 15122432);
        unsigned short* WE = (unsigned short*)((char*)d_ws + 15138816);
        hipLaunchKernelGGL(k1u, dim3(864), dim3(256), 0, stream, x, wqkv, Sp, Zp, 0);
        hipLaunchKernelGGL(k2pre, dim3(32), dim3(256), 0, stream, Sp, Zp, Ssh, Zsh);
        hipLaunchKernelGGL(k2s, dim3(2), dim3(1024), 0, stream, Ssh, Zsh, wout, wqkv, WE);
        hipLaunchKernelGGL(k3c, dim3(1728), dim3(256), 0, stream, x, WE, bout, out);
    } else {
        float* Ssh = (float*)d_ws;
        float* Zsh = (float*)((char*)d_ws + 524288);
        unsigned short* WE = (unsigned short*)((char*)d_ws + 540672);
        hipMemsetAsync(d_ws, 0, 540672, stream);  // zero shadows
        hipLaunchKernelGGL(k1u, dim3(864), dim3(256), 0, stream, x, wqkv, Ssh, Zsh, 1);
        hipLaunchKernelGGL(k2s, dim3(2), dim3(1024), 0, stream, Ssh, Zsh, wout, wqkv, WE);
        hipLaunchKernelGGL(k3c, dim3(1728), dim3(256), 0, stream, x, WE, bout, out);
    }
}